// Round 2
// baseline (341.214 us; speedup 1.0000x reference)
//
#include <hip/hip_runtime.h>
#include <hip/hip_cooperative_groups.h>
#include <math.h>

namespace cg = cooperative_groups;

// Problem constants (match reference)
#define N_PTS_C 32768
#define M_PTS_C 8192
#define EDGES_C (M_PTS_C * 64)
#define CH 35            // C_IN + 3
#define COUT 64
#define NR 4             // rings
#define KI (NR * CH)     // 140
#define CAP 64           // max valid edges stored per center (valid ~ Poisson(2.1))
#define RCUT 0.2f
#define SIG_INV 20.0f    // 1/sigma, sigma = R/N_RINGS = 0.05

// ws layout (bytes):
//   [0,       32768)    cnt[8192]          int
//   [32768,   131072)   pos_c[8192*3]      float (gathered center positions)
//   [131072,  131328)   mu[64]             float
//   [131328,  131584)   rs[64]             float
//   [131584,  4325888)  rec[8192*64]       int2 (src, dist-bits)
//   [4325888, 6423040)  a[8192*64]         float (pre-BN aggregated)

__global__ __launch_bounds__(256, 3) void k_all(
    const float* __restrict__ x, const float* __restrict__ pos,
    const int* __restrict__ idx, const int* __restrict__ esrc,
    const int* __restrict__ edst, const float* __restrict__ W,
    const float* __restrict__ gamma, const float* __restrict__ beta,
    const float* __restrict__ nbias,
    int* __restrict__ cnt, float* __restrict__ pos_c,
    float* __restrict__ mu, float* __restrict__ rs,
    int2* __restrict__ rec, float* __restrict__ a, float* __restrict__ out,
    int p_lo, int p_hi, int coop)
{
    __shared__ float Wl[KI * COUT];     // 35840 B, layout [k][o][i]
    __shared__ float Fl[16][KI];        // 8960 B
    __shared__ int   nvl[16];
    __shared__ float ss[256], sq[256];  // BN reduce

    cg::grid_group gg = cg::this_grid();
    int tid = threadIdx.x;
    int gtid = blockIdx.x * 256 + tid;
    int gsz = gridDim.x * 256;

    for (int p = p_lo; p <= p_hi; ++p) {
        if (p == 0) {
            // zero counts + precompute center positions
            for (int m = gtid; m < M_PTS_C; m += gsz) {
                cnt[m] = 0;
                int c = idx[m];
                pos_c[m*3+0] = pos[c*3+0];
                pos_c[m*3+1] = pos[c*3+1];
                pos_c[m*3+2] = pos[c*3+2];
            }
        } else if (p == 1) {
            // edge filter + compaction
            for (int e = gtid; e < EDGES_C; e += gsz) {
                int src = esrc[e];
                int dst = edst[e];
                float dx = pos[src*3+0] - pos_c[dst*3+0];
                float dy = pos[src*3+1] - pos_c[dst*3+1];
                float dz = pos[src*3+2] - pos_c[dst*3+2];
                float dist = sqrtf(dx*dx + dy*dy + dz*dz + 1e-12f);
                if (dist <= RCUT) {
                    int slot = atomicAdd(&cnt[dst], 1);
                    if (slot < CAP) rec[dst*CAP + slot] = make_int2(src, __float_as_int(dist));
                }
            }
        } else if (p == 2) {
            // continuous-kernel conv: F-accumulate per center, then LDS matvec
            for (int t = tid; t < (KI*COUT)/4; t += 256)
                ((float4*)Wl)[t] = ((const float4*)W)[t];
            for (int grp = blockIdx.x; grp < M_PTS_C/16; grp += gridDim.x) {
                __syncthreads();
                int c = tid >> 4, lane = tid & 15;
                int m = grp*16 + c;
                int nv = min(cnt[m], CAP);
                if (lane == 0) nvl[c] = nv;
                float facc[9];
                #pragma unroll
                for (int u = 0; u < 9; ++u) facc[u] = 0.f;
                for (int j = 0; j < nv; ++j) {
                    int2 r = rec[m*CAP + j];
                    int src = r.x;
                    float dist = __int_as_float(r.y);
                    float t0 = dist * SIG_INV;
                    float t1 = (dist - (float)(0.2/3.0)) * SIG_INV;
                    float t2 = (dist - (float)(0.4/3.0)) * SIG_INV;
                    float t3 = (dist - 0.2f) * SIG_INV;
                    float b0 = expf(-0.5f*t0*t0);
                    float b1 = expf(-0.5f*t1*t1);
                    float b2 = expf(-0.5f*t2*t2);
                    float b3 = expf(-0.5f*t3*t3);
                    #pragma unroll
                    for (int u = 0; u < 9; ++u) {
                        int ki = lane + u*16;
                        if (ki < KI) {
                            int k = ki / CH;
                            int i = ki - k*CH;
                            float hv = (i < 32) ? x[src*32 + i] : pos[src*3 + (i - 32)];
                            float bk = (k==0) ? b0 : (k==1) ? b1 : (k==2) ? b2 : b3;
                            facc[u] += bk * hv;
                        }
                    }
                }
                #pragma unroll
                for (int u = 0; u < 9; ++u) {
                    int ki = lane + u*16;
                    if (ki < KI) Fl[c][ki] = facc[u];
                }
                __syncthreads();
                int o = tid & 63, g = tid >> 6;
                #pragma unroll 1
                for (int r = 0; r < 4; ++r) {
                    int cc = r*4 + g;
                    float acc = 0.f;
                    #pragma unroll
                    for (int k = 0; k < NR; ++k) {
                        const float* wrow = &Wl[(k*COUT + o)*CH];
                        const float* frow = &Fl[cc][k*CH];
                        #pragma unroll
                        for (int i = 0; i < CH; ++i) acc += wrow[i] * frow[i];
                    }
                    float nvf = (float)nvl[cc];
                    a[(grp*16 + cc)*COUT + o] = acc / fmaxf(nvf, 1.f);
                }
            }
        } else if (p == 3) {
            // deterministic per-channel BN stats (identical numerics to k_bn)
            for (int o = blockIdx.x; o < COUT; o += gridDim.x) {
                float s = 0.f, q = 0.f;
                for (int m = tid; m < M_PTS_C; m += 256) {
                    float v = a[m*COUT + o];
                    s += v; q += v*v;
                }
                ss[tid] = s; sq[tid] = q;
                __syncthreads();
                for (int w = 128; w >= 1; w >>= 1) {
                    if (tid < w) { ss[tid] += ss[tid+w]; sq[tid] += sq[tid+w]; }
                    __syncthreads();
                }
                if (tid == 0) {
                    float m_ = ss[0] * (1.f / M_PTS_C);
                    float v_ = sq[0] * (1.f / M_PTS_C) - m_*m_;
                    mu[o] = m_;
                    rs[o] = rsqrtf(v_ + 1e-5f);
                }
                __syncthreads();
            }
        } else if (p == 4) {
            // BN affine + field-norm ELU, float4 I/O
            for (int flat = gtid; flat < M_PTS_C*16; flat += gsz) {
                int f = flat & 15;
                float4 v = ((const float4*)a)[flat];
                float y[4];
                float nn = 1e-12f;
                #pragma unroll
                for (int jj = 0; jj < 4; ++jj) {
                    int o = f*4 + jj;
                    float val = (jj==0) ? v.x : (jj==1) ? v.y : (jj==2) ? v.z : v.w;
                    float yy = (val - mu[o]) * rs[o] * gamma[o] + beta[o];
                    y[jj] = yy;
                    nn += yy*yy;
                }
                float n = sqrtf(nn);
                float z = n + nbias[f];
                float e = (z > 0.f) ? z : expm1f(z);
                float sc = e / n;
                float4 ov;
                ov.x = y[0]*sc; ov.y = y[1]*sc; ov.z = y[2]*sc; ov.w = y[3]*sc;
                ((float4*)out)[flat] = ov;
            }
        }
        if (p < p_hi && coop) gg.sync();
    }
}

extern "C" void kernel_launch(void* const* d_in, const int* in_sizes, int n_in,
                              void* d_out, int out_size, void* d_ws, size_t ws_size,
                              hipStream_t stream)
{
    const float* x     = (const float*)d_in[0];
    const float* pos   = (const float*)d_in[1];
    const int*   idx   = (const int*)d_in[2];
    const int*   esrc  = (const int*)d_in[3];
    const int*   edst  = (const int*)d_in[4];
    const float* W     = (const float*)d_in[5];
    const float* gamma = (const float*)d_in[6];
    const float* beta  = (const float*)d_in[7];
    const float* nbias = (const float*)d_in[8];

    char* ws = (char*)d_ws;
    int*   cnt   = (int*)ws;
    float* pos_c = (float*)(ws + 32768);
    float* mu    = (float*)(ws + 131072);
    float* rs    = (float*)(ws + 131328);
    int2*  rec   = (int2*)(ws + 131584);
    float* a     = (float*)(ws + 4325888);
    float* outp  = (float*)d_out;

    int occ = 0;
    hipError_t oe = hipOccupancyMaxActiveBlocksPerMultiprocessor(&occ, k_all, 256, 0);
    if (oe != hipSuccess || occ < 1) occ = 1;
    int grid = occ * 256;   // 256 CUs on MI355X

    int plo = 0, phi = 4, coop = 1;
    void* args[] = {
        (void*)&x, (void*)&pos, (void*)&idx, (void*)&esrc, (void*)&edst,
        (void*)&W, (void*)&gamma, (void*)&beta, (void*)&nbias,
        (void*)&cnt, (void*)&pos_c, (void*)&mu, (void*)&rs,
        (void*)&rec, (void*)&a, (void*)&outp,
        (void*)&plo, (void*)&phi, (void*)&coop
    };
    hipError_t le = hipLaunchCooperativeKernel(k_all, dim3(grid), dim3(256),
                                               args, 0, stream);
    if (le != hipSuccess) {
        // fallback: one phase per plain launch (same kernel, coop=0)
        k_all<<<32,   256, 0, stream>>>(x,pos,idx,esrc,edst,W,gamma,beta,nbias,cnt,pos_c,mu,rs,rec,a,outp,0,0,0);
        k_all<<<2048, 256, 0, stream>>>(x,pos,idx,esrc,edst,W,gamma,beta,nbias,cnt,pos_c,mu,rs,rec,a,outp,1,1,0);
        k_all<<<512,  256, 0, stream>>>(x,pos,idx,esrc,edst,W,gamma,beta,nbias,cnt,pos_c,mu,rs,rec,a,outp,2,2,0);
        k_all<<<64,   256, 0, stream>>>(x,pos,idx,esrc,edst,W,gamma,beta,nbias,cnt,pos_c,mu,rs,rec,a,outp,3,3,0);
        k_all<<<512,  256, 0, stream>>>(x,pos,idx,esrc,edst,W,gamma,beta,nbias,cnt,pos_c,mu,rs,rec,a,outp,4,4,0);
    }
}

// Round 3
// 108.956 us; speedup vs baseline: 3.1317x; 3.1317x over previous
//
#include <hip/hip_runtime.h>
#include <math.h>

// Problem constants (match reference)
#define N_PTS_C 32768
#define M_PTS_C 8192
#define EDGES_C (M_PTS_C * 64)
#define CH 35            // C_IN + 3
#define COUT 64
#define NR 4             // rings
#define KI (NR * CH)     // 140
#define CAP 64           // max valid edges per center (valid ~ Poisson(2.1))
#define RCUT 0.2f
#define SIG_INV 20.0f    // 1/sigma, sigma = R/N_RINGS = 0.05

// ws layout (bytes):
//   [0,       32768)    cnt[8192]        int
//   [32768,   33280)    sums[128]        float: sum[64] ++ sumsq[64]
//   [33280,   164352)   pos_c4[8192]     float4 (padded center positions)
//   [164352,  688640)   pos4[32768]      float4 (padded point positions)
//   [688640,  4882944)  rec[8192*64]     int2 (src, dist-bits)
//   [4882944, 6980096)  a[8192*64]       float (pre-BN aggregated)

__global__ __launch_bounds__(256) void k_init(
    const float* __restrict__ pos, const int* __restrict__ idx,
    int* __restrict__ cnt, float* __restrict__ sums,
    float4* __restrict__ pos_c4, float4* __restrict__ pos4)
{
    int gtid = blockIdx.x * 256 + threadIdx.x;
    int gsz = gridDim.x * 256;
    for (int n = gtid; n < N_PTS_C; n += gsz) {
        float4 p;
        p.x = pos[n*3+0]; p.y = pos[n*3+1]; p.z = pos[n*3+2]; p.w = 0.f;
        pos4[n] = p;
    }
    for (int m = gtid; m < M_PTS_C; m += gsz) {
        cnt[m] = 0;
        int c = idx[m];
        float4 p;
        p.x = pos[c*3+0]; p.y = pos[c*3+1]; p.z = pos[c*3+2]; p.w = 0.f;
        pos_c4[m] = p;
    }
    if (gtid < 128) sums[gtid] = 0.f;
}

__global__ __launch_bounds__(256) void k_edge(
    const float4* __restrict__ pos4, const float4* __restrict__ pos_c4,
    const int* __restrict__ esrc, const int* __restrict__ edst,
    int* __restrict__ cnt, int2* __restrict__ rec)
{
    int t = blockIdx.x * 256 + threadIdx.x;       // [0, EDGES/2)
    int2 s2 = ((const int2*)esrc)[t];
    int2 d2 = ((const int2*)edst)[t];
    #pragma unroll
    for (int q = 0; q < 2; ++q) {
        int src = (q == 0) ? s2.x : s2.y;
        int dst = (q == 0) ? d2.x : d2.y;
        float4 ps = pos4[src];
        float4 pc = pos_c4[dst];
        float dx = ps.x - pc.x, dy = ps.y - pc.y, dz = ps.z - pc.z;
        float dist = sqrtf(dx*dx + dy*dy + dz*dz + 1e-12f);
        if (dist <= RCUT) {
            int slot = atomicAdd(&cnt[dst], 1);
            if (slot < CAP) rec[dst*CAP + slot] = make_int2(src, __float_as_int(dist));
        }
    }
}

// 16 centers per block of 256 threads.
// Phase A: 16 threads/center accumulate F[140] (thread owns ki = lane+16u).
// Phase B: 4 groups of 64 threads; group g, round r computes the 64 outputs
//          of center r*4+g via LDS matvec. Then per-block partial BN sums
//          are atomically accumulated into sums[] (float atomics).
__global__ __launch_bounds__(256) void k_center(
    const float* __restrict__ x, const float* __restrict__ pos,
    const float* __restrict__ W, const int* __restrict__ cnt,
    const int2* __restrict__ rec, float* __restrict__ aout,
    float* __restrict__ sums)
{
    __shared__ float Wl[KI * COUT];     // 35840 B, layout [k][o][i]
    __shared__ float Fl[16][KI];
    __shared__ int   nvl[16];
    __shared__ float ss[256], sq[256];

    int tid = threadIdx.x;
    for (int t = tid; t < (KI*COUT)/4; t += 256)
        ((float4*)Wl)[t] = ((const float4*)W)[t];

    int m0 = blockIdx.x * 16;
    int c = tid >> 4;
    int lane = tid & 15;
    int m = m0 + c;
    int nv = min(cnt[m], CAP);
    if (lane == 0) nvl[c] = nv;

    float facc[9];
    #pragma unroll
    for (int u = 0; u < 9; ++u) facc[u] = 0.f;

    for (int j = 0; j < nv; ++j) {
        int2 r = rec[m*CAP + j];
        int src = r.x;
        float dist = __int_as_float(r.y);
        float t0 = dist * SIG_INV;
        float t1 = (dist - (float)(0.2/3.0)) * SIG_INV;
        float t2 = (dist - (float)(0.4/3.0)) * SIG_INV;
        float t3 = (dist - 0.2f) * SIG_INV;
        float b0 = expf(-0.5f*t0*t0);
        float b1 = expf(-0.5f*t1*t1);
        float b2 = expf(-0.5f*t2*t2);
        float b3 = expf(-0.5f*t3*t3);
        #pragma unroll
        for (int u = 0; u < 9; ++u) {
            int ki = lane + u*16;
            if (ki < KI) {
                int k = ki / CH;
                int i = ki - k*CH;
                float hv = (i < 32) ? x[src*32 + i] : pos[src*3 + (i - 32)];
                float bk = (k==0) ? b0 : (k==1) ? b1 : (k==2) ? b2 : b3;
                facc[u] += bk * hv;
            }
        }
    }
    #pragma unroll
    for (int u = 0; u < 9; ++u) {
        int ki = lane + u*16;
        if (ki < KI) Fl[c][ki] = facc[u];
    }
    __syncthreads();

    int o = tid & 63, g = tid >> 6;
    float psum = 0.f, psq = 0.f;
    #pragma unroll 1
    for (int r = 0; r < 4; ++r) {
        int cc = r*4 + g;
        float acc = 0.f;
        #pragma unroll
        for (int k = 0; k < NR; ++k) {
            const float* wrow = &Wl[(k*COUT + o)*CH];
            const float* frow = &Fl[cc][k*CH];
            #pragma unroll
            for (int i = 0; i < CH; ++i) acc += wrow[i] * frow[i];
        }
        float nvf = (float)nvl[cc];
        float av = acc / fmaxf(nvf, 1.f);
        aout[(m0 + cc)*COUT + o] = av;
        psum += av;
        psq  += av*av;
    }
    // per-block BN partial: reduce the 4 g-groups (same o), one atomic each
    ss[tid] = psum; sq[tid] = psq;
    __syncthreads();
    if (tid < 64) {
        float s = ss[tid] + ss[tid+64] + ss[tid+128] + ss[tid+192];
        float q = sq[tid] + sq[tid+64] + sq[tid+128] + sq[tid+192];
        atomicAdd(&sums[tid], s);
        atomicAdd(&sums[64 + tid], q);
    }
}

// BN affine (stats computed inline from sums) + field-norm ELU, float4 I/O.
__global__ __launch_bounds__(256) void k_post(
    const float* __restrict__ a, const float* __restrict__ sums,
    const float* __restrict__ gamma, const float* __restrict__ beta,
    const float* __restrict__ nbias, float* __restrict__ out)
{
    __shared__ float smu[64], srs[64], sg[64], sb[64];
    int tid = threadIdx.x;
    if (tid < 64) {
        float s = sums[tid];
        float q = sums[64 + tid];
        float m_ = s * (1.f / M_PTS_C);
        float v_ = q * (1.f / M_PTS_C) - m_*m_;
        smu[tid] = m_;
        srs[tid] = rsqrtf(v_ + 1e-5f);
        sg[tid] = gamma[tid];
        sb[tid] = beta[tid];
    }
    __syncthreads();

    int flat = blockIdx.x * 256 + tid;   // [0, M*16)
    int f = flat & 15;
    float4 v = ((const float4*)a)[flat];
    float y[4];
    float nn = 1e-12f;
    #pragma unroll
    for (int jj = 0; jj < 4; ++jj) {
        int o = f*4 + jj;
        float val = (jj==0) ? v.x : (jj==1) ? v.y : (jj==2) ? v.z : v.w;
        float yy = (val - smu[o]) * srs[o] * sg[o] + sb[o];
        y[jj] = yy;
        nn += yy*yy;
    }
    float n = sqrtf(nn);
    float z = n + nbias[f];
    float e = (z > 0.f) ? z : expm1f(z);
    float sc = e / n;
    float4 ov;
    ov.x = y[0]*sc; ov.y = y[1]*sc; ov.z = y[2]*sc; ov.w = y[3]*sc;
    ((float4*)out)[flat] = ov;
}

extern "C" void kernel_launch(void* const* d_in, const int* in_sizes, int n_in,
                              void* d_out, int out_size, void* d_ws, size_t ws_size,
                              hipStream_t stream)
{
    const float* x     = (const float*)d_in[0];
    const float* pos   = (const float*)d_in[1];
    const int*   idx   = (const int*)d_in[2];
    const int*   esrc  = (const int*)d_in[3];
    const int*   edst  = (const int*)d_in[4];
    const float* W     = (const float*)d_in[5];
    const float* gamma = (const float*)d_in[6];
    const float* beta  = (const float*)d_in[7];
    const float* nbias = (const float*)d_in[8];

    char* ws = (char*)d_ws;
    int*    cnt    = (int*)ws;
    float*  sums   = (float*)(ws + 32768);
    float4* pos_c4 = (float4*)(ws + 33280);
    float4* pos4   = (float4*)(ws + 164352);
    int2*   rec    = (int2*)(ws + 688640);
    float*  a      = (float*)(ws + 4882944);

    k_init<<<128, 256, 0, stream>>>(pos, idx, cnt, sums, pos_c4, pos4);
    k_edge<<<EDGES_C/512, 256, 0, stream>>>(pos4, pos_c4, esrc, edst, cnt, rec);
    k_center<<<M_PTS_C/16, 256, 0, stream>>>(x, pos, W, cnt, rec, a, sums);
    k_post<<<(M_PTS_C*16)/256, 256, 0, stream>>>(a, sums, gamma, beta, nbias, (float*)d_out);
}